// Round 6
// baseline (691.242 us; speedup 1.0000x reference)
//
#include <hip/hip_runtime.h>

// VectorQuantizer: z (32,256,32,32) f32, embedding (1024,256) f32.
// N=32768 rows (n = b*1024 + h*32 + w), D=256, K=1024.
// Out (f32, concat): z_q_st [8388608] (B,C,H,W), vq_loss [1], idx [32768].
// z_flat[n][c] = z[b*262144 + c*1024 + (n & 1023)]
//
// v2: register-blocked distance GEMM. Block = 64 rows x all 1024 codes
// (4 k-tiles of 256), 256 threads (tx=tid&31 over k, ty=tid>>5 over m),
// 8x8 acc per thread. E pre-transposed to eT[256][1024] (transK) so all
// LDS traffic is conflict-free float4. Reg-staged prefetch of next d-chunk
// overlaps the FMA phase. Argmin numerics identical to the passing r5 kernel:
// f32 (min1,min2,idx) + np-f32 bit-exact re-derivation for gap < TAU.
// ws: [0] loss_sum (f64); [64..4160) enorm[1024]; [4352..+1MB) eT[256][1024].

#define TAU 4.0e-4f

__device__ __forceinline__ float np_pairwise256_sq(const float* a) {
  float tot = 0.0f;
#pragma unroll
  for (int blk = 0; blk < 2; ++blk) {
    const float* p = a + blk * 128;
    float r[8];
#pragma unroll
    for (int j = 0; j < 8; ++j) r[j] = __fmul_rn(p[j], p[j]);
    for (int i = 8; i < 128; i += 8) {
#pragma unroll
      for (int j = 0; j < 8; ++j) r[j] = __fadd_rn(r[j], __fmul_rn(p[i + j], p[i + j]));
    }
    float res = __fadd_rn(__fadd_rn(__fadd_rn(r[0], r[1]), __fadd_rn(r[2], r[3])),
                          __fadd_rn(__fadd_rn(r[4], r[5]), __fadd_rn(r[6], r[7])));
    tot = (blk == 0) ? res : __fadd_rn(tot, res);
  }
  return tot;
}

__global__ void initK(double* loss_sum) { *loss_sum = 0.0; }

__global__ __launch_bounds__(256) void enormK(const float* __restrict__ emb,
                                              float* __restrict__ enorm) {
  const int k = blockIdx.x * 256 + threadIdx.x;
  enorm[k] = np_pairwise256_sq(emb + (size_t)k * 256);
}

// eT[d][k] = emb[k][d], 32x32 LDS-tiled transpose.
__global__ __launch_bounds__(256) void transK(const float* __restrict__ emb,
                                              float* __restrict__ eT) {
  __shared__ float t[32][33];
  const int k0 = blockIdx.x * 32, d0 = blockIdx.y * 32;
  const int lx = threadIdx.x & 31, ly = threadIdx.x >> 5;
#pragma unroll
  for (int r = 0; r < 4; ++r)
    t[ly + r * 8][lx] = emb[(size_t)(k0 + ly + r * 8) * 256 + d0 + lx];
  __syncthreads();
#pragma unroll
  for (int r = 0; r < 4; ++r)
    eT[(size_t)(d0 + ly + r * 8) * 1024 + k0 + lx] = t[lx][ly + r * 8];
}

__global__ __launch_bounds__(256) void fusedK(const float* __restrict__ z,
                                              const float* __restrict__ emb,
                                              const float* __restrict__ eT,
                                              const float* __restrict__ enorm,
                                              float* __restrict__ out,
                                              double* __restrict__ loss_sum) {
  __shared__ float smem[10240];  // zl[32][64] (8KB) + el[32][256] (32KB)
  __shared__ int sidx[64];
  __shared__ unsigned long long sflag;
  __shared__ float swv[4];
  __shared__ int swi[4];
  __shared__ double sloss[4];

  float* zl = smem;         // [32 d][64 m]
  float* el = smem + 2048;  // [32 d][256 k]

  const int tid = threadIdx.x;
  const int tx = tid & 31;   // k
  const int ty = tid >> 5;   // m
  const int n0 = blockIdx.x * 64;
  const int b = n0 >> 10;
  const int hw0 = n0 & 1023;
  const float* zbase = z + (size_t)b * 262144 + hw0;

  if (tid == 0) sflag = 0ull;

  float m1[8], m2[8];
  int k1[8];
#pragma unroll
  for (int i = 0; i < 8; ++i) { m1[i] = 3.0e38f; m2[i] = 3.0e38f; k1[i] = 0; }

  // ---- phase 1: distance GEMM, 4 k-tiles x 8 d-chunks, reg-staged prefetch ----
  float4 sz[2], se[8];
#pragma unroll
  for (int r = 0; r < 2; ++r) {  // chunk 0: z [32d][64m]
    int idx = r * 256 + tid;
    sz[r] = *(const float4*)(zbase + (size_t)(idx >> 4) * 1024 + (idx & 15) * 4);
  }
#pragma unroll
  for (int r = 0; r < 8; ++r) {  // chunk 0: e [32d][256k] from eT
    int idx = r * 256 + tid;
    se[r] = *(const float4*)(eT + (size_t)(idx >> 6) * 1024 + (idx & 63) * 4);
  }

  float acc[2][4][2][4];
  for (int kt = 0; kt < 4; ++kt) {
#pragma unroll
    for (int a = 0; a < 2; ++a)
#pragma unroll
      for (int i = 0; i < 4; ++i)
#pragma unroll
        for (int bb = 0; bb < 2; ++bb)
#pragma unroll
          for (int j = 0; j < 4; ++j) acc[a][i][bb][j] = 0.0f;

    for (int dc = 0; dc < 8; ++dc) {
      __syncthreads();  // previous chunk's reads done
#pragma unroll
      for (int r = 0; r < 2; ++r) {
        int idx = r * 256 + tid;
        *(float4*)(zl + (idx >> 4) * 64 + (idx & 15) * 4) = sz[r];
      }
#pragma unroll
      for (int r = 0; r < 8; ++r) {
        int idx = r * 256 + tid;
        *(float4*)(el + (idx >> 6) * 256 + (idx & 63) * 4) = se[r];
      }
      __syncthreads();
      // prefetch next chunk (overlaps FMA below)
      int nc = kt * 8 + dc + 1;
      if (nc < 32) {
        int nkt = nc >> 3, ndc = nc & 7;
#pragma unroll
        for (int r = 0; r < 2; ++r) {
          int idx = r * 256 + tid;
          sz[r] = *(const float4*)(zbase + (size_t)(ndc * 32 + (idx >> 4)) * 1024 + (idx & 15) * 4);
        }
#pragma unroll
        for (int r = 0; r < 8; ++r) {
          int idx = r * 256 + tid;
          se[r] = *(const float4*)(eT + (size_t)(ndc * 32 + (idx >> 6)) * 1024 + nkt * 256 + (idx & 63) * 4);
        }
      }
#pragma unroll 8
      for (int d = 0; d < 32; ++d) {
        float4 za = *(const float4*)(zl + d * 64 + ty * 4);
        float4 zb2 = *(const float4*)(zl + d * 64 + 32 + ty * 4);
        float4 ea = *(const float4*)(el + d * 256 + tx * 4);
        float4 eb = *(const float4*)(el + d * 256 + 128 + tx * 4);
        float zv[2][4] = {{za.x, za.y, za.z, za.w}, {zb2.x, zb2.y, zb2.z, zb2.w}};
        float ev[2][4] = {{ea.x, ea.y, ea.z, ea.w}, {eb.x, eb.y, eb.z, eb.w}};
#pragma unroll
        for (int a = 0; a < 2; ++a)
#pragma unroll
          for (int i = 0; i < 4; ++i)
#pragma unroll
            for (int bb = 0; bb < 2; ++bb)
#pragma unroll
              for (int j = 0; j < 4; ++j) acc[a][i][bb][j] += zv[a][i] * ev[bb][j];
      }
    }
    // k-tile epilogue: d' = enorm - 2*dot, update (min1,min2,idx)
    float4 e0 = *(const float4*)(enorm + kt * 256 + tx * 4);
    float4 e1 = *(const float4*)(enorm + kt * 256 + 128 + tx * 4);
    float env[2][4] = {{e0.x, e0.y, e0.z, e0.w}, {e1.x, e1.y, e1.z, e1.w}};
#pragma unroll
    for (int a = 0; a < 2; ++a)
#pragma unroll
      for (int i = 0; i < 4; ++i) {
        int ri = a * 4 + i;
#pragma unroll
        for (int bb = 0; bb < 2; ++bb)
#pragma unroll
          for (int j = 0; j < 4; ++j) {
            float v = env[bb][j] - 2.0f * acc[a][i][bb][j];
            int kg = kt * 256 + bb * 128 + tx * 4 + j;
            if (v < m1[ri]) { m2[ri] = m1[ri]; m1[ri] = v; k1[ri] = kg; }
            else if (v < m2[ri]) { m2[ri] = v; }
          }
      }
  }

  // ---- phase 2: reduce across tx (32-lane groups; ty uniform per group) ----
#pragma unroll
  for (int ri = 0; ri < 8; ++ri) {
    float a1 = m1[ri], a2 = m2[ri];
    int ai = k1[ri];
#pragma unroll
    for (int mask = 1; mask < 32; mask <<= 1) {
      float b1 = __shfl_xor(a1, mask, 32);
      float b2 = __shfl_xor(a2, mask, 32);
      int bi_ = __shfl_xor(ai, mask, 32);
      if (b1 < a1 || (b1 == a1 && bi_ < ai)) { a2 = fminf(a1, b2); a1 = b1; ai = bi_; }
      else { a2 = fminf(a2, b1); }
    }
    if (tx == 0) {
      int r = (ri >> 2) * 32 + ty * 4 + (ri & 3);
      sidx[r] = ai;
      if (a2 - a1 < TAU) atomicOr(&sflag, 1ull << r);
    }
  }
  __syncthreads();

  // ---- phase 3: np-f32 bit-exact re-derivation for flagged rows ----
  unsigned long long flags = sflag;  // uniform across block
  while (flags) {
    int r = __ffsll(flags) - 1;
    flags &= flags - 1;
    float* zrow = smem;
    __syncthreads();
    zrow[tid] = z[(size_t)b * 262144 + (size_t)tid * 1024 + hw0 + r];
    __syncthreads();
    float a32 = np_pairwise256_sq(zrow);
    // b_k: BLAS-sgemm-style sequential f32 FMA chain (ascending d), 4 chains.
    const float* er0 = emb + (size_t)(tid * 4 + 0) * 256;
    const float* er1 = emb + (size_t)(tid * 4 + 1) * 256;
    const float* er2 = emb + (size_t)(tid * 4 + 2) * 256;
    const float* er3 = emb + (size_t)(tid * 4 + 3) * 256;
    float b0 = 0.0f, b1 = 0.0f, b2 = 0.0f, b3 = 0.0f;
    for (int d = 0; d < 256; ++d) {
      float zv = zrow[d];
      b0 = __fmaf_rn(zv, er0[d], b0);
      b1 = __fmaf_rn(zv, er1[d], b1);
      b2 = __fmaf_rn(zv, er2[d], b2);
      b3 = __fmaf_rn(zv, er3[d], b3);
    }
    float bch[4] = {b0, b1, b2, b3};
    float best = 3.0e38f;
    int bi = 1 << 30;
#pragma unroll
    for (int j = 0; j < 4; ++j) {
      const int k = tid * 4 + j;  // ascending per thread -> first-index wins
      float tb = __fmul_rn(2.0f, bch[j]);
      float d32 = __fadd_rn(__fsub_rn(a32, tb), enorm[k]);
      if (d32 < best) { best = d32; bi = k; }
    }
    for (int mask = 1; mask < 64; mask <<= 1) {
      float ov = __shfl_xor(best, mask);
      int oi = __shfl_xor(bi, mask);
      if (ov < best || (ov == best && oi < bi)) { best = ov; bi = oi; }
    }
    if ((tid & 63) == 0) { swv[tid >> 6] = best; swi[tid >> 6] = bi; }
    __syncthreads();
    if (tid == 0) {
      float bv = swv[0];
      int bix = swi[0];
      for (int q = 1; q < 4; ++q)
        if (swv[q] < bv || (swv[q] == bv && swi[q] < bix)) { bv = swv[q]; bix = swi[q]; }
      sidx[r] = bix;
    }
    __syncthreads();
  }

  // ---- phase 4: outputs (f32) ----
  if (tid < 64) out[(size_t)8388609 + n0 + tid] = (float)sidx[tid];

  const int m = tid & 63;
  const int cq = tid >> 6;
  const float* erow = emb + (size_t)sidx[m] * 256;
  const size_t zb = (size_t)b * 262144 + hw0 + m;
  double acc2 = 0.0;
  for (int it = 0; it < 64; ++it) {
    int c = it * 4 + cq;
    float zv = zbase[(size_t)c * 1024 + m];
    float zq = erow[c];
    float d = zq - zv;
    out[zb + (size_t)c * 1024] = zv + d;  // z + (z_q - z), f32
    acc2 += (double)(d * d);
  }
  for (int mask = 1; mask < 64; mask <<= 1) acc2 += __shfl_xor(acc2, mask);
  if ((tid & 63) == 0) sloss[tid >> 6] = acc2;
  __syncthreads();
  if (tid == 0)
    atomicAdd(loss_sum, sloss[0] + sloss[1] + sloss[2] + sloss[3]);
}

__global__ void finalK(const double* loss_sum, float* out) {
  double s = *loss_sum;
  out[8388608] = (float)(1.25 * s / 8388608.0);  // (1+beta)*mean, beta=0.25
}

extern "C" void kernel_launch(void* const* d_in, const int* in_sizes, int n_in,
                              void* d_out, int out_size, void* d_ws, size_t ws_size,
                              hipStream_t stream) {
  const float* z = (const float*)d_in[0];
  const float* emb = (const float*)d_in[1];
  float* out = (float*)d_out;
  char* ws = (char*)d_ws;
  double* loss_sum = (double*)ws;
  float* enorm = (float*)(ws + 64);
  float* eT = (float*)(ws + 4352);  // 256x1024 f32 = 1 MB

  initK<<<1, 1, 0, stream>>>(loss_sum);
  enormK<<<4, 256, 0, stream>>>(emb, enorm);
  transK<<<dim3(32, 8), 256, 0, stream>>>(emb, eT);
  fusedK<<<512, 256, 0, stream>>>(z, emb, eT, enorm, out, loss_sum);
  finalK<<<1, 1, 0, stream>>>(loss_sum, out);
}